// Round 2
// baseline (28.254 us; speedup 1.0000x reference)
//
#include <hip/hip_runtime.h>

#define NE    16
#define INF   512
#define OUTF  512
#define NT    2048
#define OTILE 32
#define TCH   32

typedef __attribute__((ext_vector_type(4))) float f32x4;
typedef __attribute__((ext_vector_type(8))) short bf16x8;

// f32 -> bf16 (round-to-nearest-even), bit-level, self-contained
__device__ inline unsigned short f2bf(float f) {
    union { float f; unsigned u; } a; a.f = f;
    unsigned u = a.u;
    u += 0x7FFFu + ((u >> 16) & 1u);
    return (unsigned short)(u >> 16);
}

__device__ inline bf16x8 cvt8(f32x4 lo, f32x4 hi) {
    bf16x8 r;
    r[0] = (short)f2bf(lo[0]); r[1] = (short)f2bf(lo[1]);
    r[2] = (short)f2bf(lo[2]); r[3] = (short)f2bf(lo[3]);
    r[4] = (short)f2bf(hi[0]); r[5] = (short)f2bf(hi[1]);
    r[6] = (short)f2bf(hi[2]); r[7] = (short)f2bf(hi[3]);
    return r;
}

__global__ __launch_bounds__(256, 2)
void switch_linear_kernel(const float* __restrict__ x,
                          const int* __restrict__ idx,
                          const float* __restrict__ W,
                          const float* __restrict__ bias,
                          float* __restrict__ out)
{
    __shared__ int s_list[NT + TCH];
    __shared__ int s_cnt;

    const int e   = blockIdx.x;          // expert
    const int o0  = blockIdx.y * OTILE;  // output-column tile base
    const int tid = threadIdx.x;

    // ---- Phase 1: build this expert's token list in LDS ----
    if (tid == 0) s_cnt = 0;
    __syncthreads();
    for (int i = tid; i < NT; i += 256)
        if (idx[i] == e) s_list[atomicAdd(&s_cnt, 1)] = i;
    __syncthreads();
    const int cnt = s_cnt;
    const int cnt_pad = (cnt + TCH - 1) & ~(TCH - 1);
    for (int i = cnt + tid; i < cnt_pad; i += 256) s_list[i] = -1;
    __syncthreads();
    if (cnt == 0) return;

    // ---- Wave layout: 4 waves = 2 (token) x 2 (out) sub-tiles of 16 ----
    const int lane = tid & 63;
    const int wid  = tid >> 6;
    const int wt   = wid >> 1;   // token sub-tile 0..1
    const int wo   = wid & 1;    // out   sub-tile 0..1
    const int lr   = lane & 15;  // fragment row/col
    const int q    = lane >> 4;  // quarter (k-group / acc row group)

    // ---- Hoist B fragments (W rows, f32 -> bf16) into registers ----
    // B-operand: lane holds col = lane&15 (our out row of W), k = q*8 + j
    const int orow = o0 + wo * 16 + lr;
    const float* wrow = W + ((size_t)e * OUTF + orow) * INF;
    bf16x8 bfr[16];
#pragma unroll
    for (int kk = 0; kk < 16; ++kk) {
        const float* p = wrow + kk * 32 + q * 8;
        f32x4 lo = *(const f32x4*)p;
        f32x4 hi = *(const f32x4*)(p + 4);
        bfr[kk] = cvt8(lo, hi);
    }
    const float bv = bias[e * OUTF + orow];

    // ---- Phase 2: loop over 32-token chunks ----
    for (int cb = 0; cb < cnt_pad; cb += TCH) {
        const int tok_a = s_list[cb + wt * 16 + lr];
        const float* xrow = x + (size_t)(tok_a < 0 ? 0 : tok_a) * INF;
        f32x4 acc = {0.f, 0.f, 0.f, 0.f};
#pragma unroll
        for (int kk = 0; kk < 16; ++kk) {
            const float* p = xrow + kk * 32 + q * 8;
            f32x4 lo = *(const f32x4*)p;
            f32x4 hi = *(const f32x4*)(p + 4);
            bf16x8 afr = cvt8(lo, hi);
            acc = __builtin_amdgcn_mfma_f32_16x16x32_bf16(afr, bfr[kk], acc, 0, 0, 0);
        }
        // ---- Epilogue: D row = q*4+j (token), col = lr (out) ----
#pragma unroll
        for (int j = 0; j < 4; ++j) {
            const int tok = s_list[cb + wt * 16 + q * 4 + j];
            if (tok >= 0) out[(size_t)tok * OUTF + orow] = acc[j] + bv;
        }
    }
}

extern "C" void kernel_launch(void* const* d_in, const int* in_sizes, int n_in,
                              void* d_out, int out_size, void* d_ws, size_t ws_size,
                              hipStream_t stream) {
    const float* x    = (const float*)d_in[0];
    const int*   idx  = (const int*)d_in[1];
    const float* W    = (const float*)d_in[2];
    const float* bias = (const float*)d_in[3];
    float* out = (float*)d_out;

    dim3 grid(NE, OUTF / OTILE);  // 16 experts x 16 out-tiles = 256 blocks
    dim3 block(256);
    switch_linear_kernel<<<grid, block, 0, stream>>>(x, idx, W, bias, out);
}